// Round 10
// baseline (455.069 us; speedup 1.0000x reference)
//
#include <hip/hip_runtime.h>

#define DIM 64
#define NPB 128           // nodes per bucket
#define NPB_LOG 7
#define MAXNB 512         // max buckets supported by LDS tables

typedef unsigned short ushort_t;

// ============================================================================
// out[n] = ((sum_{e:dst=n} feat[src[e]]) @ W - deg[n]*(h_e@W)) / max(deg,1)
//
// Primary path (n_nodes <= 65536, ws >= featb+packed+tables):
//   K0 cc_convert : feat f32 -> bf16 table (halves gather bytes)
//   K1 cc_count   : coarse per-bucket edge counts (LDS-privatized)
//   K2 cc_scan    : exclusive scan of <=512 bucket counts (one block)
//   K3 cc_scatter : partition packed (dst<<16|src) edges into bucket regions
//   K4 cc_agg     : one block per bucket; edge-parallel gather with
//                   INDEPENDENT iterations -> ds_add_f32 into LDS acc[128][65]
//                   (stride-65: bank=(row+dim)%32, 2-way = free), then fused
//                   transform + norm epilogue from LDS. No fine CSR needed.
// ws: featb[N*64 bf16] | ccnt[512] | ccur[512] | coff[516] | packed[E]
// Fallback (big N / tiny ws): hist + single-block scan + bucket + f32 gather.
// ============================================================================

__device__ __forceinline__ ushort_t f2bf_rne(float f) {
    const unsigned u = __float_as_uint(f);
    return (ushort_t)((u + 0x7FFFu + ((u >> 16) & 1u)) >> 16);
}

// --- K0: feat -> bf16 table --------------------------------------------------
__global__ void __launch_bounds__(256)
cc_convert(const float* __restrict__ feat, ushort_t* __restrict__ featb, int n_elems) {
    int i = (blockIdx.x * blockDim.x + threadIdx.x) * 4;
    const int stride = gridDim.x * blockDim.x * 4;
    for (; i + 3 < n_elems; i += stride) {
        const float4 v = *(const float4*)&feat[i];
        ushort4 o;
        o.x = f2bf_rne(v.x); o.y = f2bf_rne(v.y);
        o.z = f2bf_rne(v.z); o.w = f2bf_rne(v.w);
        *(ushort4*)&featb[i] = o;
    }
}

// --- K1: coarse bucket histogram --------------------------------------------
__global__ void __launch_bounds__(256)
cc_count(const int* __restrict__ dst, int* __restrict__ ccnt, int n_edges, int nb) {
    __shared__ int lc[MAXNB];
    for (int i = threadIdx.x; i < nb; i += 256) lc[i] = 0;
    __syncthreads();
    int i = blockIdx.x * blockDim.x + threadIdx.x;
    const int stride = gridDim.x * blockDim.x;
    for (; i < n_edges; i += stride)
        atomicAdd(&lc[dst[i] >> NPB_LOG], 1);
    __syncthreads();
    for (int i = threadIdx.x; i < nb; i += 256)
        if (lc[i]) atomicAdd(&ccnt[i], lc[i]);
}

// --- K2: scan of bucket counts (nb <= 512, one 256-thread block) ------------
__global__ void __launch_bounds__(256)
cc_scan(const int* __restrict__ ccnt, int* __restrict__ coff, int* __restrict__ ccur,
        int nb) {
    __shared__ int wsum[4];
    const int tid = threadIdx.x, lane = tid & 63, wid = tid >> 6;
    const int i0 = tid * 2;
    const int v0 = (i0 < nb) ? ccnt[i0] : 0;
    const int v1 = (i0 + 1 < nb) ? ccnt[i0 + 1] : 0;
    const int t = v0 + v1;
    int incl = t;
    for (int off = 1; off < 64; off <<= 1) {
        const int u = __shfl_up(incl, off, 64);
        if (lane >= off) incl += u;
    }
    if (lane == 63) wsum[wid] = incl;
    __syncthreads();
    int wbase = 0;
    for (int w = 0; w < wid; ++w) wbase += wsum[w];
    const int ex = wbase + incl - t;
    if (i0 < nb)     { coff[i0]     = ex;      ccur[i0]     = ex; }
    if (i0 + 1 < nb) { coff[i0 + 1] = ex + v0; ccur[i0 + 1] = ex + v0; }
    if (tid == 255) coff[nb] = wbase + incl;   // grand total = n_edges
}

// --- K3: partition packed edges into bucket regions -------------------------
__global__ void __launch_bounds__(256)
cc_scatter(const int* __restrict__ src, const int* __restrict__ dst,
           int* __restrict__ ccur, int* __restrict__ packed,
           int n_edges, int nb) {
    __shared__ int lc[MAXNB];
    __shared__ int lbase[MAXNB];
    const int ch = (n_edges + gridDim.x - 1) / gridDim.x;
    const int lo = blockIdx.x * ch;
    const int hi = min(lo + ch, n_edges);
    for (int i = threadIdx.x; i < nb; i += 256) lc[i] = 0;
    __syncthreads();
    for (int i = lo + threadIdx.x; i < hi; i += 256)
        atomicAdd(&lc[dst[i] >> NPB_LOG], 1);
    __syncthreads();
    for (int i = threadIdx.x; i < nb; i += 256) {
        const int c = lc[i];
        lbase[i] = c ? atomicAdd(&ccur[i], c) : 0;
        lc[i] = 0;
    }
    __syncthreads();
    for (int i = lo + threadIdx.x; i < hi; i += 256) {
        const int d = dst[i];
        const int b = d >> NPB_LOG;
        const int p = lbase[b] + atomicAdd(&lc[b], 1);
        packed[p] = (int)(((unsigned)d << 16) | (unsigned)src[i]);
    }
}

// --- K4: per-bucket edge-parallel aggregation + fused transform -------------
// 512 threads (8 waves). Per wave-step: 8 edges, lane g=lane>>3 picks edge,
// dq=lane&7 picks the 16B quad of the 128B bf16 row. All steps independent
// -> deep load pipelining. ds_add_f32 into acc[ldst][dim] (stride 65).
__global__ void __launch_bounds__(512)
cc_agg(const ushort_t* __restrict__ featb, const float* __restrict__ Wg,
       const float* __restrict__ h_e, const int* __restrict__ coff,
       const int* __restrict__ packed, float* __restrict__ out, int n_nodes) {
    __shared__ float acc[NPB][DIM + 1];   // stride 65: bank=(row+dim)%32
    __shared__ float Wl[DIM * DIM];
    __shared__ int   degl[NPB];

    const int tid  = threadIdx.x;
    const int lane = tid & 63;
    const int wid  = tid >> 6;            // 0..7
    const int g    = lane >> 3;           // edge slot 0..7
    const int dq   = lane & 7;            // dim quad (8 bf16 = 16B)

    for (int i = tid; i < NPB * (DIM + 1); i += 512) ((float*)acc)[i] = 0.0f;
    for (int i = tid; i < NPB; i += 512) degl[i] = 0;
    for (int i = tid * 4; i < DIM * DIM; i += 512 * 4)
        *(float4*)&Wl[i] = *(const float4*)&Wg[i];
    __syncthreads();

    const int b  = blockIdx.x;
    const int e0 = coff[b], e1 = coff[b + 1];

    // stream edges: wave wid owns chunks [e0 + (wid + 8k)*8, +8)
    for (int base = e0 + wid * 8; base < e1; base += 64) {
        if (base + g < e1) {
            const unsigned pk = (unsigned)packed[base + g];
            const int ldst = (pk >> 16) & (NPB - 1);
            const int sidx = (int)(pk & 0xFFFFu);
            const uint4 q = *(const uint4*)&featb[(size_t)sidx * DIM + dq * 8];
            float* ap = &acc[ldst][dq * 8];
            atomicAdd(&ap[0], __uint_as_float(q.x << 16));
            atomicAdd(&ap[1], __uint_as_float(q.x & 0xFFFF0000u));
            atomicAdd(&ap[2], __uint_as_float(q.y << 16));
            atomicAdd(&ap[3], __uint_as_float(q.y & 0xFFFF0000u));
            atomicAdd(&ap[4], __uint_as_float(q.z << 16));
            atomicAdd(&ap[5], __uint_as_float(q.z & 0xFFFF0000u));
            atomicAdd(&ap[6], __uint_as_float(q.w << 16));
            atomicAdd(&ap[7], __uint_as_float(q.w & 0xFFFF0000u));
            if (dq == 0) atomicAdd(&degl[ldst], 1);
        }
    }
    __syncthreads();

    // heW[lane] = sum_k h_e[k] * W[k][lane]
    const float he = h_e[lane];
    float heW = 0.0f;
#pragma unroll
    for (int k = 0; k < DIM; ++k)
        heW += __shfl(he, k, 64) * Wl[k * DIM + lane];

    // epilogue: 16 nodes per wave; acc row read is 2-way (free) via stride 65
    const int nlo = b << NPB_LOG;
    for (int l = wid; l < NPB; l += 8) {
        const int n = nlo + l;
        if (n >= n_nodes) break;
        const float a = acc[l][lane];
        float s0 = 0.f, s1 = 0.f, s2 = 0.f, s3 = 0.f;
#pragma unroll
        for (int k = 0; k < DIM; k += 4) {
            s0 += __shfl(a, k + 0, 64) * Wl[(k + 0) * DIM + lane];
            s1 += __shfl(a, k + 1, 64) * Wl[(k + 1) * DIM + lane];
            s2 += __shfl(a, k + 2, 64) * Wl[(k + 2) * DIM + lane];
            s3 += __shfl(a, k + 3, 64) * Wl[(k + 3) * DIM + lane];
        }
        const float dg = (float)degl[l];
        out[(size_t)n * DIM + lane] =
            ((s0 + s1) + (s2 + s3) - dg * heW) / fmaxf(dg, 1.0f);
    }
}

// ============================================================================
// Fallback path (R5-proven): hist + single-block scan + atomic bucket + f32
// gather. Used only when the primary path's preconditions fail.
// ============================================================================
__global__ void __launch_bounds__(256)
compconv_hist(const int* __restrict__ dst, int* __restrict__ deg_i, int n_edges) {
    int i = blockIdx.x * blockDim.x + threadIdx.x;
    const int stride = gridDim.x * blockDim.x;
    for (; i < n_edges; i += stride)
        atomicAdd(&deg_i[dst[i]], 1);
}

__global__ void __launch_bounds__(1024)
compconv_scan1(const int* __restrict__ deg_i, int* __restrict__ offsets,
               int* __restrict__ cursor, int n) {
    __shared__ int wsum[16];
    __shared__ int s_carry;
    const int tid = threadIdx.x, lane = tid & 63, wid = tid >> 6;
    if (tid == 0) s_carry = 0;
    __syncthreads();
    const int CHUNK = 1024 * 4;
    for (int base = 0; base < n; base += CHUNK) {
        const int idx = base + tid * 4;
        int4 v = make_int4(0, 0, 0, 0);
        if (idx + 3 < n) v = *(const int4*)&deg_i[idx];
        else {
            if (idx + 0 < n) v.x = deg_i[idx + 0];
            if (idx + 1 < n) v.y = deg_i[idx + 1];
            if (idx + 2 < n) v.z = deg_i[idx + 2];
            if (idx + 3 < n) v.w = deg_i[idx + 3];
        }
        const int t = v.x + v.y + v.z + v.w;
        int incl = t;
        for (int off = 1; off < 64; off <<= 1) {
            const int u = __shfl_up(incl, off, 64);
            if (lane >= off) incl += u;
        }
        if (lane == 63) wsum[wid] = incl;
        __syncthreads();
        if (wid == 0) {
            const int w = (lane < 16) ? wsum[lane] : 0;
            int winc = w;
            for (int off = 1; off < 16; off <<= 1) {
                const int u = __shfl_up(winc, off, 64);
                if (lane >= off) winc += u;
            }
            if (lane < 16) wsum[lane] = winc - w;
        }
        __syncthreads();
        const int ex = s_carry + wsum[wid] + (incl - t);
        if (idx + 3 < n) {
            const int4 ov = make_int4(ex, ex + v.x, ex + v.x + v.y, ex + v.x + v.y + v.z);
            *(int4*)&offsets[idx] = ov;
            *(int4*)&cursor[idx]  = ov;
        } else {
            if (idx + 0 < n) { offsets[idx+0] = ex;               cursor[idx+0] = offsets[idx+0]; }
            if (idx + 1 < n) { offsets[idx+1] = ex+v.x;           cursor[idx+1] = offsets[idx+1]; }
            if (idx + 2 < n) { offsets[idx+2] = ex+v.x+v.y;       cursor[idx+2] = offsets[idx+2]; }
            if (idx + 3 < n) { offsets[idx+3] = ex+v.x+v.y+v.z;   cursor[idx+3] = offsets[idx+3]; }
        }
        __syncthreads();
        if (tid == 1023) s_carry = ex + t;
        __syncthreads();
    }
    if (tid == 0) offsets[n] = s_carry;
}

__global__ void __launch_bounds__(256)
compconv_bucket(const int* __restrict__ src, const int* __restrict__ dst,
                int* __restrict__ cursor, int* __restrict__ edge_src, int n_edges) {
    int i = blockIdx.x * blockDim.x + threadIdx.x;
    const int stride = gridDim.x * blockDim.x;
    for (; i < n_edges; i += stride) {
        const int p = atomicAdd(&cursor[dst[i]], 1);
        edge_src[p] = src[i];
    }
}

__global__ void __launch_bounds__(256)
compconv_gather(const float* __restrict__ feat, const float* __restrict__ Wg,
                const float* __restrict__ h_e, const int* __restrict__ offsets,
                const int* __restrict__ edge_src, float* __restrict__ out,
                int n_nodes) {
    __shared__ float Wl[DIM * DIM];
    for (int i = threadIdx.x * 4; i < DIM * DIM; i += blockDim.x * 4)
        *(float4*)&Wl[i] = *(const float4*)&Wg[i];
    __syncthreads();

    const int lane = threadIdx.x & 63;
    const int g    = lane >> 4;
    const int dq   = lane & 15;

    const float he = h_e[lane];
    float heW = 0.0f;
#pragma unroll
    for (int k = 0; k < DIM; ++k)
        heW += __shfl(he, k, 64) * Wl[k * DIM + lane];

    const int wave   = (blockIdx.x * blockDim.x + threadIdx.x) >> 6;
    const int nwaves = (gridDim.x * blockDim.x) >> 6;
    for (int n = wave; n < n_nodes; n += nwaves) {
        const int e0 = offsets[n];
        const int e1 = offsets[n + 1];
        float ax = 0.0f, ay = 0.0f, az = 0.0f, aw = 0.0f;
        int e = e0;
        for (; e + 8 <= e1; e += 8) {
            const int s0 = edge_src[e + g];
            const int s1 = edge_src[e + 4 + g];
            const float4 a = *(const float4*)&feat[(size_t)s0 * DIM + dq * 4];
            const float4 b = *(const float4*)&feat[(size_t)s1 * DIM + dq * 4];
            ax += a.x + b.x; ay += a.y + b.y; az += a.z + b.z; aw += a.w + b.w;
        }
        if (e + 4 <= e1) {
            const int s = edge_src[e + g];
            const float4 a = *(const float4*)&feat[(size_t)s * DIM + dq * 4];
            ax += a.x; ay += a.y; az += a.z; aw += a.w;
            e += 4;
        }
        if (g < e1 - e) {
            const int s = edge_src[e + g];
            const float4 a = *(const float4*)&feat[(size_t)s * DIM + dq * 4];
            ax += a.x; ay += a.y; az += a.z; aw += a.w;
        }
        ax += __shfl_xor(ax, 16, 64); ay += __shfl_xor(ay, 16, 64);
        az += __shfl_xor(az, 16, 64); aw += __shfl_xor(aw, 16, 64);
        ax += __shfl_xor(ax, 32, 64); ay += __shfl_xor(ay, 32, 64);
        az += __shfl_xor(az, 32, 64); aw += __shfl_xor(aw, 32, 64);

        float s = 0.0f;
#pragma unroll
        for (int q = 0; q < 16; ++q) {
            const float a0 = __shfl(ax, q, 64);
            const float a1 = __shfl(ay, q, 64);
            const float a2 = __shfl(az, q, 64);
            const float a3 = __shfl(aw, q, 64);
            s += a0 * Wl[(4 * q + 0) * DIM + lane]
               + a1 * Wl[(4 * q + 1) * DIM + lane]
               + a2 * Wl[(4 * q + 2) * DIM + lane]
               + a3 * Wl[(4 * q + 3) * DIM + lane];
        }
        const float dg = (float)(e1 - e0);
        out[(size_t)n * DIM + lane] = (s - dg * heW) / fmaxf(dg, 1.0f);
    }
}

extern "C" void kernel_launch(void* const* d_in, const int* in_sizes, int n_in,
                              void* d_out, int out_size, void* d_ws, size_t ws_size,
                              hipStream_t stream) {
    const float* feat = (const float*)d_in[0];   // (N, 64)
    const float* h_e  = (const float*)d_in[1];   // (1, 64)
    const float* W    = (const float*)d_in[2];   // (64, 64)
    const int*   src  = (const int*)d_in[3];     // (E,)
    const int*   dst  = (const int*)d_in[4];     // (E,)

    const int n_edges = in_sizes[3];
    const int n_nodes = in_sizes[0] / DIM;

    float* out = (float*)d_out;

    const int nb = (n_nodes + NPB - 1) >> NPB_LOG;

    // primary ws: featb[N*64 bf16] | ccnt[512] | ccur[512] | coff[516] | packed[E]
    const size_t featb_pad = (((size_t)n_nodes * DIM * sizeof(ushort_t)) + 15) & ~(size_t)15;
    const size_t need_new  = featb_pad + ((size_t)(512 + 512 + 516) + n_edges) * sizeof(int);
    const bool primary_ok  = (n_nodes <= 65536) && (nb <= MAXNB) && (ws_size >= need_new);

    if (primary_ok) {
        ushort_t* featb = (ushort_t*)d_ws;
        int* ints   = (int*)((char*)d_ws + featb_pad);
        int* ccnt   = ints;
        int* ccur   = ccnt + 512;
        int* coff   = ccur + 512;                  // 516 slots
        int* packed = coff + 516;

        cc_convert<<<1024, 256, 0, stream>>>(feat, featb, n_nodes * DIM);
        hipMemsetAsync(ccnt, 0, 512 * sizeof(int), stream);
        cc_count  <<<256, 256, 0, stream>>>(dst, ccnt, n_edges, nb);
        cc_scan   <<<1,   256, 0, stream>>>(ccnt, coff, ccur, nb);
        cc_scatter<<<256, 256, 0, stream>>>(src, dst, ccur, packed, n_edges, nb);
        cc_agg    <<<nb,  512, 0, stream>>>(featb, W, h_e, coff, packed, out, n_nodes);
    } else {
        // fallback: ws = deg_i[N] | cursor[N] | offsets[N+1] | edge_src[E]
        int* deg_i    = (int*)d_ws;
        int* cursor   = deg_i + n_nodes;
        int* offsets  = cursor + n_nodes;
        int* edge_src = offsets + (n_nodes + 1);

        hipMemsetAsync(deg_i, 0, (size_t)n_nodes * sizeof(int), stream);
        compconv_hist<<<1024, 256, 0, stream>>>(dst, deg_i, n_edges);
        compconv_scan1<<<1, 1024, 0, stream>>>(deg_i, offsets, cursor, n_nodes);
        compconv_bucket<<<1024, 256, 0, stream>>>(src, dst, cursor, edge_src, n_edges);
        compconv_gather<<<2048, 256, 0, stream>>>(feat, W, h_e, offsets, edge_src,
                                                  out, n_nodes);
    }
}

// Round 11
// 131.782 us; speedup vs baseline: 3.4532x; 3.4532x over previous
//
#include <hip/hip_runtime.h>

#define DIM 64
#define NPB 128           // nodes per coarse bucket (primary path)
#define NPB_LOG 7
#define MAXNB 512         // max coarse buckets supported by LDS tables

typedef unsigned short ushort_t;
typedef float f32x4 __attribute__((ext_vector_type(4)));

// ============================================================================
// out[n] = ((sum_{e:dst=n} feat[src[e]]) @ W - deg[n]*(h_e@W)) / max(deg,1)
//
// Primary path (n_nodes <= 65536):
//   K0 cc_convert : feat f32 -> bf16 table (6.4 MB)
//   K1 cc_count   : coarse per-bucket edge counts (LDS-privatized)
//   K2 cc_scan    : exclusive scan of <=512 bucket counts (one block)
//   K3 cc_scatter : partition packed (dst<<16|src) edges into bucket regions
//   K4 cc_build   : per-bucket fine CSR (dst-sorted edge_src + offsets)
//   K5a cc_gpass0 : per-node gather of edges with src in slice 0 (3.2 MB,
//                   fits one XCD L2) -> nt-store partial agg[n] (f32, d_out)
//   K5b cc_gpass1 : gather slice 1 + agg + fused transform + norm (in-place)
// Two passes keep each pass's random gathers L2-resident (R9 evidence: time
// is row-request-rate bound; L2-vs-L3 latency per row is the lever).
// ws: ccnt[512]|ccur[512]|coff[516]|offsets[Npad]|edge_src[E]|featb  (R9-proven)
// packed[E] and agg[N*64] live in d_out (temporally disjoint).
// ============================================================================

__device__ __forceinline__ ushort_t f2bf_rne(float f) {
    const unsigned u = __float_as_uint(f);
    return (ushort_t)((u + 0x7FFFu + ((u >> 16) & 1u)) >> 16);
}

// --- K0: feat -> bf16 table --------------------------------------------------
__global__ void __launch_bounds__(256)
cc_convert(const float* __restrict__ feat, ushort_t* __restrict__ featb, int n_elems) {
    int i = (blockIdx.x * blockDim.x + threadIdx.x) * 4;
    const int stride = gridDim.x * blockDim.x * 4;
    for (; i + 3 < n_elems; i += stride) {
        const float4 v = *(const float4*)&feat[i];
        ushort4 o;
        o.x = f2bf_rne(v.x); o.y = f2bf_rne(v.y);
        o.z = f2bf_rne(v.z); o.w = f2bf_rne(v.w);
        *(ushort4*)&featb[i] = o;
    }
}

// --- K1: coarse bucket histogram --------------------------------------------
__global__ void __launch_bounds__(256)
cc_count(const int* __restrict__ dst, int* __restrict__ ccnt, int n_edges, int nb) {
    __shared__ int lc[MAXNB];
    for (int i = threadIdx.x; i < nb; i += 256) lc[i] = 0;
    __syncthreads();
    int i = blockIdx.x * blockDim.x + threadIdx.x;
    const int stride = gridDim.x * blockDim.x;
    for (; i < n_edges; i += stride)
        atomicAdd(&lc[dst[i] >> NPB_LOG], 1);
    __syncthreads();
    for (int i = threadIdx.x; i < nb; i += 256)
        if (lc[i]) atomicAdd(&ccnt[i], lc[i]);
}

// --- K2: scan of bucket counts (nb <= 512, one 256-thread block) ------------
__global__ void __launch_bounds__(256)
cc_scan(const int* __restrict__ ccnt, int* __restrict__ coff, int* __restrict__ ccur,
        int nb, int* __restrict__ offsets, int n_nodes) {
    __shared__ int wsum[4];
    const int tid = threadIdx.x, lane = tid & 63, wid = tid >> 6;
    const int i0 = tid * 2;
    const int v0 = (i0 < nb) ? ccnt[i0] : 0;
    const int v1 = (i0 + 1 < nb) ? ccnt[i0 + 1] : 0;
    const int t = v0 + v1;
    int incl = t;
    for (int off = 1; off < 64; off <<= 1) {
        const int u = __shfl_up(incl, off, 64);
        if (lane >= off) incl += u;
    }
    if (lane == 63) wsum[wid] = incl;
    __syncthreads();
    int wbase = 0;
    for (int w = 0; w < wid; ++w) wbase += wsum[w];
    const int ex = wbase + incl - t;
    if (i0 < nb)     { coff[i0]     = ex;      ccur[i0]     = ex; }
    if (i0 + 1 < nb) { coff[i0 + 1] = ex + v0; ccur[i0 + 1] = ex + v0; }
    if (tid == 255) {
        const int total = wbase + incl;
        coff[nb] = total;
        offsets[n_nodes] = total;   // grand total = n_edges
    }
}

// --- K3: partition packed edges into coarse bucket regions ------------------
__global__ void __launch_bounds__(256)
cc_scatter(const int* __restrict__ src, const int* __restrict__ dst,
           int* __restrict__ ccur, int* __restrict__ packed,
           int n_edges, int nb) {
    __shared__ int lc[MAXNB];
    __shared__ int lbase[MAXNB];
    const int ch = (n_edges + gridDim.x - 1) / gridDim.x;
    const int lo = blockIdx.x * ch;
    const int hi = min(lo + ch, n_edges);
    for (int i = threadIdx.x; i < nb; i += 256) lc[i] = 0;
    __syncthreads();
    for (int i = lo + threadIdx.x; i < hi; i += 256)
        atomicAdd(&lc[dst[i] >> NPB_LOG], 1);
    __syncthreads();
    for (int i = threadIdx.x; i < nb; i += 256) {
        const int c = lc[i];
        lbase[i] = c ? atomicAdd(&ccur[i], c) : 0;
        lc[i] = 0;
    }
    __syncthreads();
    for (int i = lo + threadIdx.x; i < hi; i += 256) {
        const int d = dst[i];
        const int b = d >> NPB_LOG;
        const int p = lbase[b] + atomicAdd(&lc[b], 1);
        packed[p] = (int)(((unsigned)d << 16) | (unsigned)src[i]);
    }
}

// --- K4: per-bucket fine CSR build (one block per bucket) -------------------
__global__ void __launch_bounds__(256)
cc_build(const int* __restrict__ coff, const int* __restrict__ packed,
         int* __restrict__ offsets, int* __restrict__ edge_src, int n_nodes) {
    __shared__ int deg[NPB];
    __shared__ int loff[NPB];
    __shared__ int wsum2[2];
    const int b = blockIdx.x;
    const int nlo = b << NPB_LOG;
    const int e0 = coff[b], e1 = coff[b + 1];
    const int tid = threadIdx.x, lane = tid & 63, wid = tid >> 6;

    if (tid < NPB) deg[tid] = 0;
    __syncthreads();
    for (int i = e0 + tid; i < e1; i += 256)
        atomicAdd(&deg[(((unsigned)packed[i]) >> 16) & (NPB - 1)], 1);
    __syncthreads();

    int v = 0, incl = 0;
    if (tid < NPB) {
        v = deg[tid];
        incl = v;
        for (int off = 1; off < 64; off <<= 1) {
            const int u = __shfl_up(incl, off, 64);
            if (lane >= off) incl += u;
        }
        if (lane == 63) wsum2[wid] = incl;
    }
    __syncthreads();
    if (tid < NPB) {
        const int ex = incl - v + ((wid == 1) ? wsum2[0] : 0);
        loff[tid] = ex;
        if (nlo + tid < n_nodes) offsets[nlo + tid] = e0 + ex;
        deg[tid] = 0;                    // reuse as placement cursor
    }
    __syncthreads();
    for (int i = e0 + tid; i < e1; i += 256) {
        const int pk = packed[i];
        const int l = (((unsigned)pk) >> 16) & (NPB - 1);
        const int pos = e0 + loff[l] + atomicAdd(&deg[l], 1);
        edge_src[pos] = pk & 0xFFFF;
    }
}

// --- shared gather helper: unpack 8 bf16 -> accumulate ----------------------
#define ADD8(a, q)                                          \
    {                                                       \
        a[0] += __uint_as_float((q).x << 16);               \
        a[1] += __uint_as_float((q).x & 0xFFFF0000u);       \
        a[2] += __uint_as_float((q).y << 16);               \
        a[3] += __uint_as_float((q).y & 0xFFFF0000u);       \
        a[4] += __uint_as_float((q).z << 16);               \
        a[5] += __uint_as_float((q).z & 0xFFFF0000u);       \
        a[6] += __uint_as_float((q).w << 16);               \
        a[7] += __uint_as_float((q).w & 0xFFFF0000u);       \
    }

// --- K5a: slice-0 gather -> partial agg (f32, nt stores) --------------------
// Lane split: g=lane>>3 picks edge slot, dq=lane&7 picks 16B quad of the row.
// Both loads per 16-edge step are INDEPENDENT (no chained drain).
__global__ void __launch_bounds__(256)
cc_gpass0(const ushort_t* __restrict__ featb, const int* __restrict__ offsets,
          const int* __restrict__ edge_src, float* __restrict__ agg,
          int n_nodes, int slo, int shi) {
    const int lane = threadIdx.x & 63;
    const int g    = lane >> 3;
    const int dq   = lane & 7;

    const int wave   = (blockIdx.x * blockDim.x + threadIdx.x) >> 6;
    const int nwaves = (gridDim.x * blockDim.x) >> 6;
    for (int n = wave; n < n_nodes; n += nwaves) {
        const int e0 = offsets[n];
        const int e1 = offsets[n + 1];
        float a[8] = {0.f, 0.f, 0.f, 0.f, 0.f, 0.f, 0.f, 0.f};
        for (int e = e0; e < e1; e += 16) {
            const int p0 = e + g;
            const int p1 = e + 8 + g;
            const int s0 = (p0 < e1) ? edge_src[p0] : -1;
            const int s1 = (p1 < e1) ? edge_src[p1] : -1;
            if (s0 >= slo && s0 < shi) {
                const uint4 q = *(const uint4*)&featb[(size_t)s0 * DIM + dq * 8];
                ADD8(a, q);
            }
            if (s1 >= slo && s1 < shi) {
                const uint4 q = *(const uint4*)&featb[(size_t)s1 * DIM + dq * 8];
                ADD8(a, q);
            }
        }
#pragma unroll
        for (int c = 0; c < 8; ++c) {
            a[c] += __shfl_xor(a[c], 8, 64);
            a[c] += __shfl_xor(a[c], 16, 64);
            a[c] += __shfl_xor(a[c], 32, 64);
        }
        if (g == 0) {   // lanes 0..7: each writes 8 consecutive dims (32B)
            f32x4 v0 = {a[0], a[1], a[2], a[3]};
            f32x4 v1 = {a[4], a[5], a[6], a[7]};
            __builtin_nontemporal_store(v0, (f32x4*)&agg[(size_t)n * DIM + dq * 8]);
            __builtin_nontemporal_store(v1, (f32x4*)&agg[(size_t)n * DIM + dq * 8 + 4]);
        }
    }
}

// --- K5b: slice-1 gather + agg + fused transform + norm (in-place on agg) ---
__global__ void __launch_bounds__(256)
cc_gpass1(const ushort_t* __restrict__ featb, const float* __restrict__ Wg,
          const float* __restrict__ h_e, const int* __restrict__ offsets,
          const int* __restrict__ edge_src, float* __restrict__ out,
          int n_nodes, int slo, int shi) {
    __shared__ float Wl[DIM * DIM];
    for (int i = threadIdx.x * 4; i < DIM * DIM; i += blockDim.x * 4)
        *(float4*)&Wl[i] = *(const float4*)&Wg[i];
    __syncthreads();

    const int lane = threadIdx.x & 63;
    const int g    = lane >> 3;
    const int dq   = lane & 7;

    const float he = h_e[lane];
    float heW = 0.0f;
#pragma unroll
    for (int k = 0; k < DIM; ++k)
        heW += __shfl(he, k, 64) * Wl[k * DIM + lane];

    const int wave   = (blockIdx.x * blockDim.x + threadIdx.x) >> 6;
    const int nwaves = (gridDim.x * blockDim.x) >> 6;
    for (int n = wave; n < n_nodes; n += nwaves) {
        const int e0 = offsets[n];
        const int e1 = offsets[n + 1];
        float a[8] = {0.f, 0.f, 0.f, 0.f, 0.f, 0.f, 0.f, 0.f};
        for (int e = e0; e < e1; e += 16) {
            const int p0 = e + g;
            const int p1 = e + 8 + g;
            const int s0 = (p0 < e1) ? edge_src[p0] : -1;
            const int s1 = (p1 < e1) ? edge_src[p1] : -1;
            if (s0 >= slo && s0 < shi) {
                const uint4 q = *(const uint4*)&featb[(size_t)s0 * DIM + dq * 8];
                ADD8(a, q);
            }
            if (s1 >= slo && s1 < shi) {
                const uint4 q = *(const uint4*)&featb[(size_t)s1 * DIM + dq * 8];
                ADD8(a, q);
            }
        }
#pragma unroll
        for (int c = 0; c < 8; ++c) {
            a[c] += __shfl_xor(a[c], 8, 64);
            a[c] += __shfl_xor(a[c], 16, 64);
            a[c] += __shfl_xor(a[c], 32, 64);
        }
        // add pass-0 partial (each lane reads its dq-quad; 8B-distinct addrs)
        {
            const f32x4 p0 = __builtin_nontemporal_load(
                (const f32x4*)&out[(size_t)n * DIM + dq * 8]);
            const f32x4 p1 = __builtin_nontemporal_load(
                (const f32x4*)&out[(size_t)n * DIM + dq * 8 + 4]);
            a[0] += p0.x; a[1] += p0.y; a[2] += p0.z; a[3] += p0.w;
            a[4] += p1.x; a[5] += p1.y; a[6] += p1.z; a[7] += p1.w;
        }
        // transform: s[lane] = sum_k agg_k * W[k][lane]
        // agg_k lives in a[k&7] of lane (k>>3)  (g==0 group holds dq=0..7)
        float s = 0.0f;
#pragma unroll
        for (int k = 0; k < DIM; ++k)
            s += __shfl(a[k & 7], k >> 3, 64) * Wl[k * DIM + lane];

        const float dg = (float)(e1 - e0);
        __builtin_nontemporal_store((s - dg * heW) / fmaxf(dg, 1.0f),
                                    &out[(size_t)n * DIM + lane]);
    }
}

// ============================================================================
// Fallback path (R5-proven): hist + single-block scan + atomic bucket + f32
// gather. Used only when the primary path's preconditions fail.
// ============================================================================
__global__ void __launch_bounds__(256)
compconv_hist(const int* __restrict__ dst, int* __restrict__ deg_i, int n_edges) {
    int i = blockIdx.x * blockDim.x + threadIdx.x;
    const int stride = gridDim.x * blockDim.x;
    for (; i < n_edges; i += stride)
        atomicAdd(&deg_i[dst[i]], 1);
}

__global__ void __launch_bounds__(1024)
compconv_scan1(const int* __restrict__ deg_i, int* __restrict__ offsets,
               int* __restrict__ cursor, int n) {
    __shared__ int wsum[16];
    __shared__ int s_carry;
    const int tid = threadIdx.x, lane = tid & 63, wid = tid >> 6;
    if (tid == 0) s_carry = 0;
    __syncthreads();
    const int CHUNK = 1024 * 4;
    for (int base = 0; base < n; base += CHUNK) {
        const int idx = base + tid * 4;
        int4 v = make_int4(0, 0, 0, 0);
        if (idx + 3 < n) v = *(const int4*)&deg_i[idx];
        else {
            if (idx + 0 < n) v.x = deg_i[idx + 0];
            if (idx + 1 < n) v.y = deg_i[idx + 1];
            if (idx + 2 < n) v.z = deg_i[idx + 2];
            if (idx + 3 < n) v.w = deg_i[idx + 3];
        }
        const int t = v.x + v.y + v.z + v.w;
        int incl = t;
        for (int off = 1; off < 64; off <<= 1) {
            const int u = __shfl_up(incl, off, 64);
            if (lane >= off) incl += u;
        }
        if (lane == 63) wsum[wid] = incl;
        __syncthreads();
        if (wid == 0) {
            const int w = (lane < 16) ? wsum[lane] : 0;
            int winc = w;
            for (int off = 1; off < 16; off <<= 1) {
                const int u = __shfl_up(winc, off, 64);
                if (lane >= off) winc += u;
            }
            if (lane < 16) wsum[lane] = winc - w;
        }
        __syncthreads();
        const int ex = s_carry + wsum[wid] + (incl - t);
        if (idx + 3 < n) {
            const int4 ov = make_int4(ex, ex + v.x, ex + v.x + v.y, ex + v.x + v.y + v.z);
            *(int4*)&offsets[idx] = ov;
            *(int4*)&cursor[idx]  = ov;
        } else {
            if (idx + 0 < n) { offsets[idx+0] = ex;               cursor[idx+0] = offsets[idx+0]; }
            if (idx + 1 < n) { offsets[idx+1] = ex+v.x;           cursor[idx+1] = offsets[idx+1]; }
            if (idx + 2 < n) { offsets[idx+2] = ex+v.x+v.y;       cursor[idx+2] = offsets[idx+2]; }
            if (idx + 3 < n) { offsets[idx+3] = ex+v.x+v.y+v.z;   cursor[idx+3] = offsets[idx+3]; }
        }
        __syncthreads();
        if (tid == 1023) s_carry = ex + t;
        __syncthreads();
    }
    if (tid == 0) offsets[n] = s_carry;
}

__global__ void __launch_bounds__(256)
compconv_bucket(const int* __restrict__ src, const int* __restrict__ dst,
                int* __restrict__ cursor, int* __restrict__ edge_src, int n_edges) {
    int i = blockIdx.x * blockDim.x + threadIdx.x;
    const int stride = gridDim.x * blockDim.x;
    for (; i < n_edges; i += stride) {
        const int p = atomicAdd(&cursor[dst[i]], 1);
        edge_src[p] = src[i];
    }
}

__global__ void __launch_bounds__(256)
compconv_gather(const float* __restrict__ feat, const float* __restrict__ Wg,
                const float* __restrict__ h_e, const int* __restrict__ offsets,
                const int* __restrict__ edge_src, float* __restrict__ out,
                int n_nodes) {
    __shared__ float Wl[DIM * DIM];
    for (int i = threadIdx.x * 4; i < DIM * DIM; i += blockDim.x * 4)
        *(float4*)&Wl[i] = *(const float4*)&Wg[i];
    __syncthreads();

    const int lane = threadIdx.x & 63;
    const int g    = lane >> 4;
    const int dq   = lane & 15;

    const float he = h_e[lane];
    float heW = 0.0f;
#pragma unroll
    for (int k = 0; k < DIM; ++k)
        heW += __shfl(he, k, 64) * Wl[k * DIM + lane];

    const int wave   = (blockIdx.x * blockDim.x + threadIdx.x) >> 6;
    const int nwaves = (gridDim.x * blockDim.x) >> 6;
    for (int n = wave; n < n_nodes; n += nwaves) {
        const int e0 = offsets[n];
        const int e1 = offsets[n + 1];
        float ax = 0.0f, ay = 0.0f, az = 0.0f, aw = 0.0f;
        int e = e0;
        for (; e + 8 <= e1; e += 8) {
            const int s0 = edge_src[e + g];
            const int s1 = edge_src[e + 4 + g];
            const float4 a = *(const float4*)&feat[(size_t)s0 * DIM + dq * 4];
            const float4 b = *(const float4*)&feat[(size_t)s1 * DIM + dq * 4];
            ax += a.x + b.x; ay += a.y + b.y; az += a.z + b.z; aw += a.w + b.w;
        }
        if (e + 4 <= e1) {
            const int s = edge_src[e + g];
            const float4 a = *(const float4*)&feat[(size_t)s * DIM + dq * 4];
            ax += a.x; ay += a.y; az += a.z; aw += a.w;
            e += 4;
        }
        if (g < e1 - e) {
            const int s = edge_src[e + g];
            const float4 a = *(const float4*)&feat[(size_t)s * DIM + dq * 4];
            ax += a.x; ay += a.y; az += a.z; aw += a.w;
        }
        ax += __shfl_xor(ax, 16, 64); ay += __shfl_xor(ay, 16, 64);
        az += __shfl_xor(az, 16, 64); aw += __shfl_xor(aw, 16, 64);
        ax += __shfl_xor(ax, 32, 64); ay += __shfl_xor(ay, 32, 64);
        az += __shfl_xor(az, 32, 64); aw += __shfl_xor(aw, 32, 64);

        float s = 0.0f;
#pragma unroll
        for (int q = 0; q < 16; ++q) {
            const float a0 = __shfl(ax, q, 64);
            const float a1 = __shfl(ay, q, 64);
            const float a2 = __shfl(az, q, 64);
            const float a3 = __shfl(aw, q, 64);
            s += a0 * Wl[(4 * q + 0) * DIM + lane]
               + a1 * Wl[(4 * q + 1) * DIM + lane]
               + a2 * Wl[(4 * q + 2) * DIM + lane]
               + a3 * Wl[(4 * q + 3) * DIM + lane];
        }
        const float dg = (float)(e1 - e0);
        out[(size_t)n * DIM + lane] = (s - dg * heW) / fmaxf(dg, 1.0f);
    }
}

extern "C" void kernel_launch(void* const* d_in, const int* in_sizes, int n_in,
                              void* d_out, int out_size, void* d_ws, size_t ws_size,
                              hipStream_t stream) {
    const float* feat = (const float*)d_in[0];   // (N, 64)
    const float* h_e  = (const float*)d_in[1];   // (1, 64)
    const float* W    = (const float*)d_in[2];   // (64, 64)
    const int*   src  = (const int*)d_in[3];     // (E,)
    const int*   dst  = (const int*)d_in[4];     // (E,)

    const int n_edges = in_sizes[3];
    const int n_nodes = in_sizes[0] / DIM;

    float* out = (float*)d_out;

    const int nb = (n_nodes + NPB - 1) >> NPB_LOG;
    const int n_off_pad = (n_nodes + 4) & ~3;

    // ws: ccnt[512] | ccur[512] | coff[516] | offsets[Npad] | edge_src[E] | featb
    const size_t need_cc = ((size_t)(512 + 512 + 516) + n_off_pad + n_edges) * sizeof(int);
    const size_t need_bf = need_cc + (size_t)n_nodes * DIM * sizeof(ushort_t);
    const bool primary_ok = (n_nodes <= 65536) && (nb <= MAXNB) &&
                            (out_size >= n_nodes * DIM) && (out_size >= n_edges) &&
                            (ws_size >= need_bf);

    if (primary_ok) {
        int* ccnt     = (int*)d_ws;
        int* ccur     = ccnt + 512;
        int* coff     = ccur + 512;                // 516 slots
        int* offsets  = coff + 516;
        int* edge_src = offsets + n_off_pad;
        ushort_t* featb = (ushort_t*)(edge_src + n_edges);
        int* packed   = (int*)d_out;               // dead before gpass0 writes agg
        float* agg    = out;                       // partial sums live in d_out

        const int split = (n_nodes + 1) / 2;       // slice: split*128B <= 3.3MB

        cc_convert<<<1024, 256, 0, stream>>>(feat, featb, n_nodes * DIM);
        hipMemsetAsync(ccnt, 0, 512 * sizeof(int), stream);
        cc_count  <<<256, 256, 0, stream>>>(dst, ccnt, n_edges, nb);
        cc_scan   <<<1,   256, 0, stream>>>(ccnt, coff, ccur, nb, offsets, n_nodes);
        cc_scatter<<<256, 256, 0, stream>>>(src, dst, ccur, packed, n_edges, nb);
        cc_build  <<<nb,  256, 0, stream>>>(coff, packed, offsets, edge_src, n_nodes);
        cc_gpass0 <<<2048, 256, 0, stream>>>(featb, offsets, edge_src, agg,
                                             n_nodes, 0, split);
        cc_gpass1 <<<2048, 256, 0, stream>>>(featb, W, h_e, offsets, edge_src,
                                             out, n_nodes, split, n_nodes);
    } else {
        // fallback: ws = deg_i[N] | cursor[N] | offsets[N+1] | edge_src[E]
        int* deg_i    = (int*)d_ws;
        int* cursor   = deg_i + n_nodes;
        int* offsets  = cursor + n_nodes;
        int* edge_src = offsets + (n_nodes + 1);

        hipMemsetAsync(deg_i, 0, (size_t)n_nodes * sizeof(int), stream);
        compconv_hist<<<1024, 256, 0, stream>>>(dst, deg_i, n_edges);
        compconv_scan1<<<1, 1024, 0, stream>>>(deg_i, offsets, cursor, n_nodes);
        compconv_bucket<<<1024, 256, 0, stream>>>(src, dst, cursor, edge_src, n_edges);
        compconv_gather<<<2048, 256, 0, stream>>>(feat, W, h_e, offsets, edge_src,
                                                  out, n_nodes);
    }
}

// Round 12
// 83.764 us; speedup vs baseline: 5.4327x; 1.5732x over previous
//
#include <hip/hip_runtime.h>

#define DIM 64
#define NPB 128           // nodes per coarse bucket (primary path)
#define NPB_LOG 7
#define MAXNB 512         // max coarse buckets supported by LDS tables

typedef unsigned short ushort_t;
typedef float f32x4 __attribute__((ext_vector_type(4)));

// ============================================================================
// out[n] = ((sum_{e:dst=n} feat[src[e]]) @ W - deg[n]*(h_e@W)) / max(deg,1)
//
// Primary path (n_nodes <= 65536):
//   K0 cc_convert : feat f32 -> bf16 table (6.4 MB)
//   K1..K4        : CSR build (count/scan/scatter/build) — R9-proven
//   K5 cc_gather8 : 8-lane-group-per-node gather. NO shuffles, NO LDS:
//                   lane (g,dq) accumulates dims 8dq..8dq+7 of node base+g.
//                   Writes f32 agg to d_out.
//   K6 cc_xform   : block-tiled GEMM agg@W (64 nodes/block, LDS tiles,
//                   4x4 acc per thread) + (-deg*heW, /max(deg,1)) epilogue,
//                   in-place on d_out. deg from offsets.
// R11 evidence: the old fused per-node shfl transform was ~45 us of LDS-pipe
// serialization; gather itself runs ~20 G rows/s.
// ws: ccnt[512]|ccur[512]|coff[516]|offsets[Npad]|edge_src[E]|featb (R9-proven)
// packed[E] and agg[N*64] live in d_out (temporally disjoint).
// ============================================================================

__device__ __forceinline__ ushort_t f2bf_rne(float f) {
    const unsigned u = __float_as_uint(f);
    return (ushort_t)((u + 0x7FFFu + ((u >> 16) & 1u)) >> 16);
}

// --- K0: feat -> bf16 table --------------------------------------------------
__global__ void __launch_bounds__(256)
cc_convert(const float* __restrict__ feat, ushort_t* __restrict__ featb, int n_elems) {
    int i = (blockIdx.x * blockDim.x + threadIdx.x) * 4;
    const int stride = gridDim.x * blockDim.x * 4;
    for (; i + 3 < n_elems; i += stride) {
        const float4 v = *(const float4*)&feat[i];
        ushort4 o;
        o.x = f2bf_rne(v.x); o.y = f2bf_rne(v.y);
        o.z = f2bf_rne(v.z); o.w = f2bf_rne(v.w);
        *(ushort4*)&featb[i] = o;
    }
}

// --- K1: coarse bucket histogram --------------------------------------------
__global__ void __launch_bounds__(256)
cc_count(const int* __restrict__ dst, int* __restrict__ ccnt, int n_edges, int nb) {
    __shared__ int lc[MAXNB];
    for (int i = threadIdx.x; i < nb; i += 256) lc[i] = 0;
    __syncthreads();
    int i = blockIdx.x * blockDim.x + threadIdx.x;
    const int stride = gridDim.x * blockDim.x;
    for (; i < n_edges; i += stride)
        atomicAdd(&lc[dst[i] >> NPB_LOG], 1);
    __syncthreads();
    for (int i = threadIdx.x; i < nb; i += 256)
        if (lc[i]) atomicAdd(&ccnt[i], lc[i]);
}

// --- K2: scan of bucket counts (nb <= 512, one 256-thread block) ------------
__global__ void __launch_bounds__(256)
cc_scan(const int* __restrict__ ccnt, int* __restrict__ coff, int* __restrict__ ccur,
        int nb, int* __restrict__ offsets, int n_nodes) {
    __shared__ int wsum[4];
    const int tid = threadIdx.x, lane = tid & 63, wid = tid >> 6;
    const int i0 = tid * 2;
    const int v0 = (i0 < nb) ? ccnt[i0] : 0;
    const int v1 = (i0 + 1 < nb) ? ccnt[i0 + 1] : 0;
    const int t = v0 + v1;
    int incl = t;
    for (int off = 1; off < 64; off <<= 1) {
        const int u = __shfl_up(incl, off, 64);
        if (lane >= off) incl += u;
    }
    if (lane == 63) wsum[wid] = incl;
    __syncthreads();
    int wbase = 0;
    for (int w = 0; w < wid; ++w) wbase += wsum[w];
    const int ex = wbase + incl - t;
    if (i0 < nb)     { coff[i0]     = ex;      ccur[i0]     = ex; }
    if (i0 + 1 < nb) { coff[i0 + 1] = ex + v0; ccur[i0 + 1] = ex + v0; }
    if (tid == 255) {
        const int total = wbase + incl;
        coff[nb] = total;
        offsets[n_nodes] = total;   // grand total = n_edges
    }
}

// --- K3: partition packed edges into coarse bucket regions ------------------
__global__ void __launch_bounds__(256)
cc_scatter(const int* __restrict__ src, const int* __restrict__ dst,
           int* __restrict__ ccur, int* __restrict__ packed,
           int n_edges, int nb) {
    __shared__ int lc[MAXNB];
    __shared__ int lbase[MAXNB];
    const int ch = (n_edges + gridDim.x - 1) / gridDim.x;
    const int lo = blockIdx.x * ch;
    const int hi = min(lo + ch, n_edges);
    for (int i = threadIdx.x; i < nb; i += 256) lc[i] = 0;
    __syncthreads();
    for (int i = lo + threadIdx.x; i < hi; i += 256)
        atomicAdd(&lc[dst[i] >> NPB_LOG], 1);
    __syncthreads();
    for (int i = threadIdx.x; i < nb; i += 256) {
        const int c = lc[i];
        lbase[i] = c ? atomicAdd(&ccur[i], c) : 0;
        lc[i] = 0;
    }
    __syncthreads();
    for (int i = lo + threadIdx.x; i < hi; i += 256) {
        const int d = dst[i];
        const int b = d >> NPB_LOG;
        const int p = lbase[b] + atomicAdd(&lc[b], 1);
        packed[p] = (int)(((unsigned)d << 16) | (unsigned)src[i]);
    }
}

// --- K4: per-bucket fine CSR build (one block per bucket) -------------------
__global__ void __launch_bounds__(256)
cc_build(const int* __restrict__ coff, const int* __restrict__ packed,
         int* __restrict__ offsets, int* __restrict__ edge_src, int n_nodes) {
    __shared__ int deg[NPB];
    __shared__ int loff[NPB];
    __shared__ int wsum2[2];
    const int b = blockIdx.x;
    const int nlo = b << NPB_LOG;
    const int e0 = coff[b], e1 = coff[b + 1];
    const int tid = threadIdx.x, lane = tid & 63, wid = tid >> 6;

    if (tid < NPB) deg[tid] = 0;
    __syncthreads();
    for (int i = e0 + tid; i < e1; i += 256)
        atomicAdd(&deg[(((unsigned)packed[i]) >> 16) & (NPB - 1)], 1);
    __syncthreads();

    int v = 0, incl = 0;
    if (tid < NPB) {
        v = deg[tid];
        incl = v;
        for (int off = 1; off < 64; off <<= 1) {
            const int u = __shfl_up(incl, off, 64);
            if (lane >= off) incl += u;
        }
        if (lane == 63) wsum2[wid] = incl;
    }
    __syncthreads();
    if (tid < NPB) {
        const int ex = incl - v + ((wid == 1) ? wsum2[0] : 0);
        loff[tid] = ex;
        if (nlo + tid < n_nodes) offsets[nlo + tid] = e0 + ex;
        deg[tid] = 0;                    // reuse as placement cursor
    }
    __syncthreads();
    for (int i = e0 + tid; i < e1; i += 256) {
        const int pk = packed[i];
        const int l = (((unsigned)pk) >> 16) & (NPB - 1);
        const int pos = e0 + loff[l] + atomicAdd(&deg[l], 1);
        edge_src[pos] = pk & 0xFFFF;
    }
}

// --- shared helper: unpack 8 bf16 -> accumulate ------------------------------
#define ADD8(a, q)                                          \
    {                                                       \
        a[0] += __uint_as_float((q).x << 16);               \
        a[1] += __uint_as_float((q).x & 0xFFFF0000u);       \
        a[2] += __uint_as_float((q).y << 16);               \
        a[3] += __uint_as_float((q).y & 0xFFFF0000u);       \
        a[4] += __uint_as_float((q).z << 16);               \
        a[5] += __uint_as_float((q).z & 0xFFFF0000u);       \
        a[6] += __uint_as_float((q).w << 16);               \
        a[7] += __uint_as_float((q).w & 0xFFFF0000u);       \
    }

// --- K5: gather, 8-lane group per node, no shuffles --------------------------
// lane = (g=lane>>3 -> node slot, dq=lane&7 -> dims 8dq..8dq+7).
// Group g walks node (base+g)'s edge list; 2 independent loads per step.
// Lane's a[8] is final -> direct 32B store. Divergence across groups is
// bounded by maxdeg of 8 nodes (~1.4x meandeg).
__global__ void __launch_bounds__(256)
cc_gather8(const ushort_t* __restrict__ featb, const int* __restrict__ offsets,
           const int* __restrict__ edge_src, float* __restrict__ agg,
           int n_nodes) {
    const int lane = threadIdx.x & 63;
    const int g    = lane >> 3;
    const int dq   = lane & 7;

    const int wave   = (blockIdx.x * blockDim.x + threadIdx.x) >> 6;
    const int nwaves = (gridDim.x * blockDim.x) >> 6;
    for (int nb = wave * 8; nb < n_nodes; nb += nwaves * 8) {
        const int n = nb + g;
        const bool valid = (n < n_nodes);
        const int e0 = valid ? offsets[n] : 0;
        const int e1 = valid ? offsets[n + 1] : 0;
        float a[8] = {0.f, 0.f, 0.f, 0.f, 0.f, 0.f, 0.f, 0.f};
        int e = e0;
        for (; e + 2 <= e1; e += 2) {          // two independent chains
            const int s0 = edge_src[e];
            const int s1 = edge_src[e + 1];
            const uint4 q0 = *(const uint4*)&featb[(size_t)s0 * DIM + dq * 8];
            const uint4 q1 = *(const uint4*)&featb[(size_t)s1 * DIM + dq * 8];
            ADD8(a, q0);
            ADD8(a, q1);
        }
        if (e < e1) {
            const int s = edge_src[e];
            const uint4 q = *(const uint4*)&featb[(size_t)s * DIM + dq * 8];
            ADD8(a, q);
        }
        if (valid) {
            f32x4 v0 = {a[0], a[1], a[2], a[3]};
            f32x4 v1 = {a[4], a[5], a[6], a[7]};
            *(f32x4*)&agg[(size_t)n * DIM + dq * 8]     = v0;
            *(f32x4*)&agg[(size_t)n * DIM + dq * 8 + 4] = v1;
        }
    }
}

// --- K6: block-tiled transform: io = (io @ W - deg*heW) / max(deg,1) --------
// 64 nodes per block, in-place. LDS: W (16KB) + agg tile [64][68] (17KB).
// Thread (tx=t&15, ty=t>>4) computes a 4x4 sub-tile: rows 4ty.., cols 4tx..
__global__ void __launch_bounds__(256)
cc_xform(const float* __restrict__ Wg, const float* __restrict__ h_e,
         const int* __restrict__ offsets, float* __restrict__ io, int n_nodes) {
    __shared__ float Wl[DIM * DIM];
    __shared__ float At[64][68];          // stride 68: rows 16B-aligned
    __shared__ float heWl[DIM];

    const int t = threadIdx.x;
    for (int i = t * 4; i < DIM * DIM; i += 256 * 4)
        *(float4*)&Wl[i] = *(const float4*)&Wg[i];
    __syncthreads();

    if (t < DIM) {                        // heW once per block (1 wave)
        float s = 0.f;
        for (int k = 0; k < DIM; ++k) s += h_e[k] * Wl[k * DIM + t];
        heWl[t] = s;
    }

    const int n0 = blockIdx.x * 64;
    const int r = t >> 2;                 // 0..63 tile row
    const int q = t & 3;                  // 16-float chunk
    if (n0 + r < n_nodes) {
        const float4* srcp = (const float4*)&io[(size_t)(n0 + r) * DIM + q * 16];
        const float4 v0 = srcp[0], v1 = srcp[1], v2 = srcp[2], v3 = srcp[3];
        *(float4*)&At[r][q * 16 + 0]  = v0;
        *(float4*)&At[r][q * 16 + 4]  = v1;
        *(float4*)&At[r][q * 16 + 8]  = v2;
        *(float4*)&At[r][q * 16 + 12] = v3;
    }
    __syncthreads();

    const int tx = t & 15, ty = t >> 4;
    float acc[4][4] = {{0.f}};
#pragma unroll 8
    for (int k = 0; k < DIM; ++k) {
        const float4 bv = *(const float4*)&Wl[k * DIM + tx * 4];
        const float a0 = At[ty * 4 + 0][k];
        const float a1 = At[ty * 4 + 1][k];
        const float a2 = At[ty * 4 + 2][k];
        const float a3 = At[ty * 4 + 3][k];
        acc[0][0] += a0 * bv.x; acc[0][1] += a0 * bv.y; acc[0][2] += a0 * bv.z; acc[0][3] += a0 * bv.w;
        acc[1][0] += a1 * bv.x; acc[1][1] += a1 * bv.y; acc[1][2] += a1 * bv.z; acc[1][3] += a1 * bv.w;
        acc[2][0] += a2 * bv.x; acc[2][1] += a2 * bv.y; acc[2][2] += a2 * bv.z; acc[2][3] += a2 * bv.w;
        acc[3][0] += a3 * bv.x; acc[3][1] += a3 * bv.y; acc[3][2] += a3 * bv.z; acc[3][3] += a3 * bv.w;
    }

    const float hw0 = heWl[tx * 4 + 0], hw1 = heWl[tx * 4 + 1];
    const float hw2 = heWl[tx * 4 + 2], hw3 = heWl[tx * 4 + 3];
#pragma unroll
    for (int i = 0; i < 4; ++i) {
        const int n = n0 + ty * 4 + i;
        if (n < n_nodes) {
            const float dg = (float)(offsets[n + 1] - offsets[n]);
            const float rd = 1.0f / fmaxf(dg, 1.0f);
            float4 o;
            o.x = (acc[i][0] - dg * hw0) * rd;
            o.y = (acc[i][1] - dg * hw1) * rd;
            o.z = (acc[i][2] - dg * hw2) * rd;
            o.w = (acc[i][3] - dg * hw3) * rd;
            *(float4*)&io[(size_t)n * DIM + tx * 4] = o;
        }
    }
}

// ============================================================================
// Fallback path (R5-proven): hist + single-block scan + atomic bucket + f32
// gather. Used only when the primary path's preconditions fail.
// ============================================================================
__global__ void __launch_bounds__(256)
compconv_hist(const int* __restrict__ dst, int* __restrict__ deg_i, int n_edges) {
    int i = blockIdx.x * blockDim.x + threadIdx.x;
    const int stride = gridDim.x * blockDim.x;
    for (; i < n_edges; i += stride)
        atomicAdd(&deg_i[dst[i]], 1);
}

__global__ void __launch_bounds__(1024)
compconv_scan1(const int* __restrict__ deg_i, int* __restrict__ offsets,
               int* __restrict__ cursor, int n) {
    __shared__ int wsum[16];
    __shared__ int s_carry;
    const int tid = threadIdx.x, lane = tid & 63, wid = tid >> 6;
    if (tid == 0) s_carry = 0;
    __syncthreads();
    const int CHUNK = 1024 * 4;
    for (int base = 0; base < n; base += CHUNK) {
        const int idx = base + tid * 4;
        int4 v = make_int4(0, 0, 0, 0);
        if (idx + 3 < n) v = *(const int4*)&deg_i[idx];
        else {
            if (idx + 0 < n) v.x = deg_i[idx + 0];
            if (idx + 1 < n) v.y = deg_i[idx + 1];
            if (idx + 2 < n) v.z = deg_i[idx + 2];
            if (idx + 3 < n) v.w = deg_i[idx + 3];
        }
        const int t = v.x + v.y + v.z + v.w;
        int incl = t;
        for (int off = 1; off < 64; off <<= 1) {
            const int u = __shfl_up(incl, off, 64);
            if (lane >= off) incl += u;
        }
        if (lane == 63) wsum[wid] = incl;
        __syncthreads();
        if (wid == 0) {
            const int w = (lane < 16) ? wsum[lane] : 0;
            int winc = w;
            for (int off = 1; off < 16; off <<= 1) {
                const int u = __shfl_up(winc, off, 64);
                if (lane >= off) winc += u;
            }
            if (lane < 16) wsum[lane] = winc - w;
        }
        __syncthreads();
        const int ex = s_carry + wsum[wid] + (incl - t);
        if (idx + 3 < n) {
            const int4 ov = make_int4(ex, ex + v.x, ex + v.x + v.y, ex + v.x + v.y + v.z);
            *(int4*)&offsets[idx] = ov;
            *(int4*)&cursor[idx]  = ov;
        } else {
            if (idx + 0 < n) { offsets[idx+0] = ex;               cursor[idx+0] = offsets[idx+0]; }
            if (idx + 1 < n) { offsets[idx+1] = ex+v.x;           cursor[idx+1] = offsets[idx+1]; }
            if (idx + 2 < n) { offsets[idx+2] = ex+v.x+v.y;       cursor[idx+2] = offsets[idx+2]; }
            if (idx + 3 < n) { offsets[idx+3] = ex+v.x+v.y+v.z;   cursor[idx+3] = offsets[idx+3]; }
        }
        __syncthreads();
        if (tid == 1023) s_carry = ex + t;
        __syncthreads();
    }
    if (tid == 0) offsets[n] = s_carry;
}

__global__ void __launch_bounds__(256)
compconv_bucket(const int* __restrict__ src, const int* __restrict__ dst,
                int* __restrict__ cursor, int* __restrict__ edge_src, int n_edges) {
    int i = blockIdx.x * blockDim.x + threadIdx.x;
    const int stride = gridDim.x * blockDim.x;
    for (; i < n_edges; i += stride) {
        const int p = atomicAdd(&cursor[dst[i]], 1);
        edge_src[p] = src[i];
    }
}

__global__ void __launch_bounds__(256)
compconv_gather(const float* __restrict__ feat, const float* __restrict__ Wg,
                const float* __restrict__ h_e, const int* __restrict__ offsets,
                const int* __restrict__ edge_src, float* __restrict__ out,
                int n_nodes) {
    __shared__ float Wl[DIM * DIM];
    for (int i = threadIdx.x * 4; i < DIM * DIM; i += blockDim.x * 4)
        *(float4*)&Wl[i] = *(const float4*)&Wg[i];
    __syncthreads();

    const int lane = threadIdx.x & 63;
    const int g    = lane >> 4;
    const int dq   = lane & 15;

    const float he = h_e[lane];
    float heW = 0.0f;
#pragma unroll
    for (int k = 0; k < DIM; ++k)
        heW += __shfl(he, k, 64) * Wl[k * DIM + lane];

    const int wave   = (blockIdx.x * blockDim.x + threadIdx.x) >> 6;
    const int nwaves = (gridDim.x * blockDim.x) >> 6;
    for (int n = wave; n < n_nodes; n += nwaves) {
        const int e0 = offsets[n];
        const int e1 = offsets[n + 1];
        float ax = 0.0f, ay = 0.0f, az = 0.0f, aw = 0.0f;
        int e = e0;
        for (; e + 8 <= e1; e += 8) {
            const int s0 = edge_src[e + g];
            const int s1 = edge_src[e + 4 + g];
            const float4 a = *(const float4*)&feat[(size_t)s0 * DIM + dq * 4];
            const float4 b = *(const float4*)&feat[(size_t)s1 * DIM + dq * 4];
            ax += a.x + b.x; ay += a.y + b.y; az += a.z + b.z; aw += a.w + b.w;
        }
        if (e + 4 <= e1) {
            const int s = edge_src[e + g];
            const float4 a = *(const float4*)&feat[(size_t)s * DIM + dq * 4];
            ax += a.x; ay += a.y; az += a.z; aw += a.w;
            e += 4;
        }
        if (g < e1 - e) {
            const int s = edge_src[e + g];
            const float4 a = *(const float4*)&feat[(size_t)s * DIM + dq * 4];
            ax += a.x; ay += a.y; az += a.z; aw += a.w;
        }
        ax += __shfl_xor(ax, 16, 64); ay += __shfl_xor(ay, 16, 64);
        az += __shfl_xor(az, 16, 64); aw += __shfl_xor(aw, 16, 64);
        ax += __shfl_xor(ax, 32, 64); ay += __shfl_xor(ay, 32, 64);
        az += __shfl_xor(az, 32, 64); aw += __shfl_xor(aw, 32, 64);

        float s = 0.0f;
#pragma unroll
        for (int q = 0; q < 16; ++q) {
            const float a0 = __shfl(ax, q, 64);
            const float a1 = __shfl(ay, q, 64);
            const float a2 = __shfl(az, q, 64);
            const float a3 = __shfl(aw, q, 64);
            s += a0 * Wl[(4 * q + 0) * DIM + lane]
               + a1 * Wl[(4 * q + 1) * DIM + lane]
               + a2 * Wl[(4 * q + 2) * DIM + lane]
               + a3 * Wl[(4 * q + 3) * DIM + lane];
        }
        const float dg = (float)(e1 - e0);
        out[(size_t)n * DIM + lane] = (s - dg * heW) / fmaxf(dg, 1.0f);
    }
}

extern "C" void kernel_launch(void* const* d_in, const int* in_sizes, int n_in,
                              void* d_out, int out_size, void* d_ws, size_t ws_size,
                              hipStream_t stream) {
    const float* feat = (const float*)d_in[0];   // (N, 64)
    const float* h_e  = (const float*)d_in[1];   // (1, 64)
    const float* W    = (const float*)d_in[2];   // (64, 64)
    const int*   src  = (const int*)d_in[3];     // (E,)
    const int*   dst  = (const int*)d_in[4];     // (E,)

    const int n_edges = in_sizes[3];
    const int n_nodes = in_sizes[0] / DIM;

    float* out = (float*)d_out;

    const int nb = (n_nodes + NPB - 1) >> NPB_LOG;
    const int n_off_pad = (n_nodes + 4) & ~3;

    // ws: ccnt[512] | ccur[512] | coff[516] | offsets[Npad] | edge_src[E] | featb
    const size_t need_cc = ((size_t)(512 + 512 + 516) + n_off_pad + n_edges) * sizeof(int);
    const size_t need_bf = need_cc + (size_t)n_nodes * DIM * sizeof(ushort_t);
    const bool primary_ok = (n_nodes <= 65536) && (nb <= MAXNB) &&
                            (out_size >= n_nodes * DIM) && (out_size >= n_edges) &&
                            (ws_size >= need_bf);

    if (primary_ok) {
        int* ccnt     = (int*)d_ws;
        int* ccur     = ccnt + 512;
        int* coff     = ccur + 512;                // 516 slots
        int* offsets  = coff + 516;
        int* edge_src = offsets + n_off_pad;
        ushort_t* featb = (ushort_t*)(edge_src + n_edges);
        int* packed   = (int*)d_out;               // dead before gather writes agg
        float* agg    = out;                       // f32 sums live in d_out

        cc_convert<<<1024, 256, 0, stream>>>(feat, featb, n_nodes * DIM);
        hipMemsetAsync(ccnt, 0, 512 * sizeof(int), stream);
        cc_count  <<<256, 256, 0, stream>>>(dst, ccnt, n_edges, nb);
        cc_scan   <<<1,   256, 0, stream>>>(ccnt, coff, ccur, nb, offsets, n_nodes);
        cc_scatter<<<256, 256, 0, stream>>>(src, dst, ccur, packed, n_edges, nb);
        cc_build  <<<nb,  256, 0, stream>>>(coff, packed, offsets, edge_src, n_nodes);

        const int gblocks = (n_nodes + 31) / 32;   // 4 waves x 8 nodes per block
        cc_gather8<<<gblocks, 256, 0, stream>>>(featb, offsets, edge_src, agg, n_nodes);
        const int xblocks = (n_nodes + 63) / 64;
        cc_xform  <<<xblocks, 256, 0, stream>>>(W, h_e, offsets, out, n_nodes);
    } else {
        // fallback: ws = deg_i[N] | cursor[N] | offsets[N+1] | edge_src[E]
        int* deg_i    = (int*)d_ws;
        int* cursor   = deg_i + n_nodes;
        int* offsets  = cursor + n_nodes;
        int* edge_src = offsets + (n_nodes + 1);

        hipMemsetAsync(deg_i, 0, (size_t)n_nodes * sizeof(int), stream);
        compconv_hist<<<1024, 256, 0, stream>>>(dst, deg_i, n_edges);
        compconv_scan1<<<1, 1024, 0, stream>>>(deg_i, offsets, cursor, n_nodes);
        compconv_bucket<<<1024, 256, 0, stream>>>(src, dst, cursor, edge_src, n_edges);
        compconv_gather<<<2048, 256, 0, stream>>>(feat, W, h_e, offsets, edge_src,
                                                  out, n_nodes);
    }
}

// Round 14
// 77.273 us; speedup vs baseline: 5.8891x; 1.0840x over previous
//
#include <hip/hip_runtime.h>

#define DIM 64
#define NPB 64            // nodes per bucket (primary path)
#define NPB_LOG 6
#define MAXNB 1024        // max buckets supported by LDS tables
#define ECAP 2048         // per-bucket edge capacity in LDS (mean 1023 here)

typedef unsigned short ushort_t;
typedef float f32x4 __attribute__((ext_vector_type(4)));

// ============================================================================
// out[n] = ((sum_{e:dst=n} feat[src[e]]) @ W - deg[n]*(h_e@W)) / max(deg,1)
//
// Primary path (n_nodes <= 65536), 5 dispatches:
//   K1 cc_prep    : feat f32 -> bf16 table + zero ccnt (folded memset)
//   K2 cc_count   : coarse per-bucket edge counts (LDS-privatized)
//   K3 cc_scan    : exclusive scan of <=1024 bucket counts (one block)
//   K4 cc_scatter : partition packed (dst<<16|src) edges into bucket regions
//   K5 cc_fused   : per bucket (64 nodes): packed->LDS, hist+scan+place sorted
//                   src list in LDS, register gather (8-lane groups, LDS-
//                   broadcast indices), LDS At tile, block-tiled GEMM @W +
//                   (-deg*heW)/max(deg,1) epilogue -> out. No global
//                   intermediates (edge_src/offsets/agg all eliminated).
// R12 evidence: no single kernel dominates; dispatch count + agg/edge_src
// round-trips are first-order. ws: ccnt|ccur|coff|packed[E]|featb = 9.61 MB.
// d_out is write-only (final result).
// ============================================================================

__device__ __forceinline__ ushort_t f2bf_rne(float f) {
    const unsigned u = __float_as_uint(f);
    return (ushort_t)((u + 0x7FFFu + ((u >> 16) & 1u)) >> 16);
}

// --- K1: feat -> bf16 table, and zero the bucket-count table ----------------
__global__ void __launch_bounds__(256)
cc_prep(const float* __restrict__ feat, ushort_t* __restrict__ featb,
        int n_elems, int* __restrict__ ccnt) {
    if (blockIdx.x == 0)
        for (int i = threadIdx.x; i < MAXNB; i += 256) ccnt[i] = 0;
    int i = (blockIdx.x * blockDim.x + threadIdx.x) * 4;
    const int stride = gridDim.x * blockDim.x * 4;
    for (; i + 3 < n_elems; i += stride) {
        const float4 v = *(const float4*)&feat[i];
        ushort4 o;
        o.x = f2bf_rne(v.x); o.y = f2bf_rne(v.y);
        o.z = f2bf_rne(v.z); o.w = f2bf_rne(v.w);
        *(ushort4*)&featb[i] = o;
    }
}

// --- K2: coarse bucket histogram --------------------------------------------
__global__ void __launch_bounds__(256)
cc_count(const int* __restrict__ dst, int* __restrict__ ccnt, int n_edges, int nb) {
    __shared__ int lc[MAXNB];
    for (int i = threadIdx.x; i < nb; i += 256) lc[i] = 0;
    __syncthreads();
    int i = blockIdx.x * blockDim.x + threadIdx.x;
    const int stride = gridDim.x * blockDim.x;
    for (; i < n_edges; i += stride)
        atomicAdd(&lc[dst[i] >> NPB_LOG], 1);
    __syncthreads();
    for (int i = threadIdx.x; i < nb; i += 256)
        if (lc[i]) atomicAdd(&ccnt[i], lc[i]);
}

// --- K3: exclusive scan of <=1024 bucket counts (one 256-thread block) ------
__global__ void __launch_bounds__(256)
cc_scan(const int* __restrict__ ccnt, int* __restrict__ coff, int* __restrict__ ccur,
        int nb) {
    __shared__ int wsum[4];
    const int tid = threadIdx.x, lane = tid & 63, wid = tid >> 6;
    const int i0 = tid * 4;
    const int v0 = (i0     < nb) ? ccnt[i0]     : 0;
    const int v1 = (i0 + 1 < nb) ? ccnt[i0 + 1] : 0;
    const int v2 = (i0 + 2 < nb) ? ccnt[i0 + 2] : 0;
    const int v3 = (i0 + 3 < nb) ? ccnt[i0 + 3] : 0;
    const int tt = v0 + v1 + v2 + v3;
    int incl = tt;
    for (int off = 1; off < 64; off <<= 1) {
        const int u = __shfl_up(incl, off, 64);
        if (lane >= off) incl += u;
    }
    if (lane == 63) wsum[wid] = incl;
    __syncthreads();
    int wbase = 0;
    for (int w = 0; w < wid; ++w) wbase += wsum[w];
    const int ex = wbase + incl - tt;
    if (i0     < nb) { coff[i0]     = ex;                ccur[i0]     = ex; }
    if (i0 + 1 < nb) { coff[i0 + 1] = ex + v0;           ccur[i0 + 1] = ex + v0; }
    if (i0 + 2 < nb) { coff[i0 + 2] = ex + v0 + v1;      ccur[i0 + 2] = ex + v0 + v1; }
    if (i0 + 3 < nb) { coff[i0 + 3] = ex + v0 + v1 + v2; ccur[i0 + 3] = ex + v0 + v1 + v2; }
    if (tid == 255) coff[nb] = wbase + incl;   // grand total = n_edges
}

// --- K4: partition packed edges into coarse bucket regions ------------------
__global__ void __launch_bounds__(256)
cc_scatter(const int* __restrict__ src, const int* __restrict__ dst,
           int* __restrict__ ccur, int* __restrict__ packed,
           int n_edges, int nb) {
    __shared__ int lc[MAXNB];
    __shared__ int lbase[MAXNB];
    const int ch = (n_edges + gridDim.x - 1) / gridDim.x;
    const int lo = blockIdx.x * ch;
    const int hi = min(lo + ch, n_edges);
    for (int i = threadIdx.x; i < nb; i += 256) lc[i] = 0;
    __syncthreads();
    for (int i = lo + threadIdx.x; i < hi; i += 256)
        atomicAdd(&lc[dst[i] >> NPB_LOG], 1);
    __syncthreads();
    for (int i = threadIdx.x; i < nb; i += 256) {
        const int c = lc[i];
        lbase[i] = c ? atomicAdd(&ccur[i], c) : 0;
        lc[i] = 0;
    }
    __syncthreads();
    for (int i = lo + threadIdx.x; i < hi; i += 256) {
        const int d = dst[i];
        const int b = d >> NPB_LOG;
        const int p = lbase[b] + atomicAdd(&lc[b], 1);
        packed[p] = (int)(((unsigned)d << 16) | (unsigned)src[i]);
    }
}

// --- shared helper: unpack 8 bf16 -> accumulate ------------------------------
#define ADD8(a, q)                                          \
    {                                                       \
        a[0] += __uint_as_float((q).x << 16);               \
        a[1] += __uint_as_float((q).x & 0xFFFF0000u);       \
        a[2] += __uint_as_float((q).y << 16);               \
        a[3] += __uint_as_float((q).y & 0xFFFF0000u);       \
        a[4] += __uint_as_float((q).z << 16);               \
        a[5] += __uint_as_float((q).z & 0xFFFF0000u);       \
        a[6] += __uint_as_float((q).w << 16);               \
        a[7] += __uint_as_float((q).w & 0xFFFF0000u);       \
    }

// --- K5: fused build + gather + transform, one block per 64-node bucket -----
// LDS 51.2 KB -> 3 blocks/CU. Phases:
//  A: packed run -> esl_in (LDS) + degree histogram
//  B: wave0: 64-wide scan -> loff, zero cur | wave1: heW = h_e @ W
//  C: place sorted src list esl (LDS)
//  D: gather — 32 8-lane groups x 2 nodes; esl index reads are LDS broadcasts;
//     per-lane a[8] = final 8 dims -> 2x f32x4 LDS writes into At
//  E: block-tiled GEMM At@W (thread = 4x4 subtile) + norm epilogue -> out
__global__ void __launch_bounds__(256)
cc_fused(const ushort_t* __restrict__ featb, const float* __restrict__ Wg,
         const float* __restrict__ h_e, const int* __restrict__ coff,
         const int* __restrict__ packed, float* __restrict__ out, int n_nodes) {
    __shared__ float Wl[DIM * DIM];       // 16 KB
    __shared__ float At[NPB][DIM + 4];    // 17 KB (stride 68)
    __shared__ int   esl_in[ECAP];        // 8 KB
    __shared__ int   esl[ECAP];           // 8 KB (dst-sorted src)
    __shared__ int   deg[NPB];
    __shared__ int   loff[NPB];
    __shared__ int   cur[NPB];
    __shared__ float heWl[DIM];

    const int t   = threadIdx.x;
    const int b   = blockIdx.x;
    const int e0  = coff[b];
    const int cnt = coff[b + 1] - e0;
    const bool fits = (cnt <= ECAP);

    for (int i = t * 4; i < DIM * DIM; i += 1024)
        *(float4*)&Wl[i] = *(const float4*)&Wg[i];
    if (t < NPB) deg[t] = 0;
    __syncthreads();

    // A: stage + histogram
    for (int i = t; i < cnt; i += 256) {
        const int pk = packed[e0 + i];
        if (fits) esl_in[i] = pk;
        atomicAdd(&deg[(((unsigned)pk) >> 16) & (NPB - 1)], 1);
    }
    __syncthreads();

    // B: scan (wave 0) and heW (wave 1)
    if (t < 64) {
        const int v = deg[t];
        int incl = v;
        for (int off = 1; off < 64; off <<= 1) {
            const int u = __shfl_up(incl, off, 64);
            if (t >= off) incl += u;
        }
        loff[t] = incl - v;
        cur[t]  = 0;
    } else if (t < 128) {
        const int c = t - 64;
        float s = 0.f;
        for (int k = 0; k < DIM; ++k) s += h_e[k] * Wl[k * DIM + c];
        heWl[c] = s;
    }
    __syncthreads();

    // C: place sorted src list
    if (fits) {
        for (int i = t; i < cnt; i += 256) {
            const int pk = esl_in[i];
            const int l  = (((unsigned)pk) >> 16) & (NPB - 1);
            esl[loff[l] + atomicAdd(&cur[l], 1)] = pk & 0xFFFF;
        }
    }
    __syncthreads();

    // D: gather
    const int grp = t >> 3;          // 0..31
    const int dq  = t & 7;           // dims 8dq..8dq+7
#pragma unroll
    for (int half = 0; half < 2; ++half) {
        const int l  = grp + half * 32;
        const int d0 = loff[l];
        const int dn = deg[l];
        float a[8] = {0.f, 0.f, 0.f, 0.f, 0.f, 0.f, 0.f, 0.f};
        if (fits) {
            int e = 0;
            for (; e + 2 <= dn; e += 2) {           // 2 independent loads
                const int s0 = esl[d0 + e];
                const int s1 = esl[d0 + e + 1];
                const uint4 q0 = *(const uint4*)&featb[(size_t)s0 * DIM + dq * 8];
                const uint4 q1 = *(const uint4*)&featb[(size_t)s1 * DIM + dq * 8];
                ADD8(a, q0);
                ADD8(a, q1);
            }
            if (e < dn) {
                const int s = esl[d0 + e];
                const uint4 q = *(const uint4*)&featb[(size_t)s * DIM + dq * 8];
                ADD8(a, q);
            }
        } else {
            // overflow slow path (statistically never; correct always):
            // scan the whole bucket from global, filter by node
            for (int i = 0; i < cnt; ++i) {
                const int pk = packed[e0 + i];
                if ((int)((((unsigned)pk) >> 16) & (NPB - 1)) == l) {
                    const uint4 q =
                        *(const uint4*)&featb[(size_t)(pk & 0xFFFF) * DIM + dq * 8];
                    ADD8(a, q);
                }
            }
        }
        const f32x4 v0 = {a[0], a[1], a[2], a[3]};
        const f32x4 v1 = {a[4], a[5], a[6], a[7]};
        *(f32x4*)&At[l][dq * 8]     = v0;
        *(f32x4*)&At[l][dq * 8 + 4] = v1;
    }
    __syncthreads();

    // E: GEMM + epilogue (R12-proven cc_xform body)
    const int tx = t & 15, ty = t >> 4;
    float acc[4][4] = {{0.f}};
#pragma unroll 8
    for (int k = 0; k < DIM; ++k) {
        const float4 bv = *(const float4*)&Wl[k * DIM + tx * 4];
        const float a0 = At[ty * 4 + 0][k];
        const float a1 = At[ty * 4 + 1][k];
        const float a2 = At[ty * 4 + 2][k];
        const float a3 = At[ty * 4 + 3][k];
        acc[0][0] += a0 * bv.x; acc[0][1] += a0 * bv.y; acc[0][2] += a0 * bv.z; acc[0][3] += a0 * bv.w;
        acc[1][0] += a1 * bv.x; acc[1][1] += a1 * bv.y; acc[1][2] += a1 * bv.z; acc[1][3] += a1 * bv.w;
        acc[2][0] += a2 * bv.x; acc[2][1] += a2 * bv.y; acc[2][2] += a2 * bv.z; acc[2][3] += a2 * bv.w;
        acc[3][0] += a3 * bv.x; acc[3][1] += a3 * bv.y; acc[3][2] += a3 * bv.z; acc[3][3] += a3 * bv.w;
    }
    const float hw0 = heWl[tx * 4 + 0], hw1 = heWl[tx * 4 + 1];
    const float hw2 = heWl[tx * 4 + 2], hw3 = heWl[tx * 4 + 3];
    const int n0 = b << NPB_LOG;
#pragma unroll
    for (int i = 0; i < 4; ++i) {
        const int n = n0 + ty * 4 + i;
        if (n < n_nodes) {
            const float dg = (float)deg[ty * 4 + i];
            const float rd = 1.0f / fmaxf(dg, 1.0f);
            float4 o;
            o.x = (acc[i][0] - dg * hw0) * rd;
            o.y = (acc[i][1] - dg * hw1) * rd;
            o.z = (acc[i][2] - dg * hw2) * rd;
            o.w = (acc[i][3] - dg * hw3) * rd;
            *(float4*)&out[(size_t)n * DIM + tx * 4] = o;
        }
    }
}

// ============================================================================
// Fallback path (R5-proven): hist + single-block scan + atomic bucket + f32
// gather. Used only when the primary path's preconditions fail.
// ============================================================================
__global__ void __launch_bounds__(256)
compconv_hist(const int* __restrict__ dst, int* __restrict__ deg_i, int n_edges) {
    int i = blockIdx.x * blockDim.x + threadIdx.x;
    const int stride = gridDim.x * blockDim.x;
    for (; i < n_edges; i += stride)
        atomicAdd(&deg_i[dst[i]], 1);
}

__global__ void __launch_bounds__(1024)
compconv_scan1(const int* __restrict__ deg_i, int* __restrict__ offsets,
               int* __restrict__ cursor, int n) {
    __shared__ int wsum[16];
    __shared__ int s_carry;
    const int tid = threadIdx.x, lane = tid & 63, wid = tid >> 6;
    if (tid == 0) s_carry = 0;
    __syncthreads();
    const int CHUNK = 1024 * 4;
    for (int base = 0; base < n; base += CHUNK) {
        const int idx = base + tid * 4;
        int4 v = make_int4(0, 0, 0, 0);
        if (idx + 3 < n) v = *(const int4*)&deg_i[idx];
        else {
            if (idx + 0 < n) v.x = deg_i[idx + 0];
            if (idx + 1 < n) v.y = deg_i[idx + 1];
            if (idx + 2 < n) v.z = deg_i[idx + 2];
            if (idx + 3 < n) v.w = deg_i[idx + 3];
        }
        const int t = v.x + v.y + v.z + v.w;
        int incl = t;
        for (int off = 1; off < 64; off <<= 1) {
            const int u = __shfl_up(incl, off, 64);
            if (lane >= off) incl += u;
        }
        if (lane == 63) wsum[wid] = incl;
        __syncthreads();
        if (wid == 0) {
            const int w = (lane < 16) ? wsum[lane] : 0;
            int winc = w;
            for (int off = 1; off < 16; off <<= 1) {
                const int u = __shfl_up(winc, off, 64);
                if (lane >= off) winc += u;
            }
            if (lane < 16) wsum[lane] = winc - w;
        }
        __syncthreads();
        const int ex = s_carry + wsum[wid] + (incl - t);
        if (idx + 3 < n) {
            const int4 ov = make_int4(ex, ex + v.x, ex + v.x + v.y, ex + v.x + v.y + v.z);
            *(int4*)&offsets[idx] = ov;
            *(int4*)&cursor[idx]  = ov;
        } else {
            if (idx + 0 < n) { offsets[idx+0] = ex;               cursor[idx+0] = offsets[idx+0]; }
            if (idx + 1 < n) { offsets[idx+1] = ex+v.x;           cursor[idx+1] = offsets[idx+1]; }
            if (idx + 2 < n) { offsets[idx+2] = ex+v.x+v.y;       cursor[idx+2] = offsets[idx+2]; }
            if (idx + 3 < n) { offsets[idx+3] = ex+v.x+v.y+v.z;   cursor[idx+3] = offsets[idx+3]; }
        }
        __syncthreads();
        if (tid == 1023) s_carry = ex + t;
        __syncthreads();
    }
    if (tid == 0) offsets[n] = s_carry;
}

__global__ void __launch_bounds__(256)
compconv_bucket(const int* __restrict__ src, const int* __restrict__ dst,
                int* __restrict__ cursor, int* __restrict__ edge_src, int n_edges) {
    int i = blockIdx.x * blockDim.x + threadIdx.x;
    const int stride = gridDim.x * blockDim.x;
    for (; i < n_edges; i += stride) {
        const int p = atomicAdd(&cursor[dst[i]], 1);
        edge_src[p] = src[i];
    }
}

__global__ void __launch_bounds__(256)
compconv_gather(const float* __restrict__ feat, const float* __restrict__ Wg,
                const float* __restrict__ h_e, const int* __restrict__ offsets,
                const int* __restrict__ edge_src, float* __restrict__ out,
                int n_nodes) {
    __shared__ float Wl[DIM * DIM];
    for (int i = threadIdx.x * 4; i < DIM * DIM; i += blockDim.x * 4)
        *(float4*)&Wl[i] = *(const float4*)&Wg[i];
    __syncthreads();

    const int lane = threadIdx.x & 63;
    const int g    = lane >> 4;
    const int dq   = lane & 15;

    const float he = h_e[lane];
    float heW = 0.0f;
#pragma unroll
    for (int k = 0; k < DIM; ++k)
        heW += __shfl(he, k, 64) * Wl[k * DIM + lane];

    const int wave   = (blockIdx.x * blockDim.x + threadIdx.x) >> 6;
    const int nwaves = (gridDim.x * blockDim.x) >> 6;
    for (int n = wave; n < n_nodes; n += nwaves) {
        const int e0 = offsets[n];
        const int e1 = offsets[n + 1];
        float ax = 0.0f, ay = 0.0f, az = 0.0f, aw = 0.0f;
        int e = e0;
        for (; e + 8 <= e1; e += 8) {
            const int s0 = edge_src[e + g];
            const int s1 = edge_src[e + 4 + g];
            const float4 a = *(const float4*)&feat[(size_t)s0 * DIM + dq * 4];
            const float4 b = *(const float4*)&feat[(size_t)s1 * DIM + dq * 4];
            ax += a.x + b.x; ay += a.y + b.y; az += a.z + b.z; aw += a.w + b.w;
        }
        if (e + 4 <= e1) {
            const int s = edge_src[e + g];
            const float4 a = *(const float4*)&feat[(size_t)s * DIM + dq * 4];
            ax += a.x; ay += a.y; az += a.z; aw += a.w;
            e += 4;
        }
        if (g < e1 - e) {
            const int s = edge_src[e + g];
            const float4 a = *(const float4*)&feat[(size_t)s * DIM + dq * 4];
            ax += a.x; ay += a.y; az += a.z; aw += a.w;
        }
        ax += __shfl_xor(ax, 16, 64); ay += __shfl_xor(ay, 16, 64);
        az += __shfl_xor(az, 16, 64); aw += __shfl_xor(aw, 16, 64);
        ax += __shfl_xor(ax, 32, 64); ay += __shfl_xor(ay, 32, 64);
        az += __shfl_xor(az, 32, 64); aw += __shfl_xor(aw, 32, 64);

        float s = 0.0f;
#pragma unroll
        for (int q = 0; q < 16; ++q) {
            const float a0 = __shfl(ax, q, 64);
            const float a1 = __shfl(ay, q, 64);
            const float a2 = __shfl(az, q, 64);
            const float a3 = __shfl(aw, q, 64);
            s += a0 * Wl[(4 * q + 0) * DIM + lane]
               + a1 * Wl[(4 * q + 1) * DIM + lane]
               + a2 * Wl[(4 * q + 2) * DIM + lane]
               + a3 * Wl[(4 * q + 3) * DIM + lane];
        }
        const float dg = (float)(e1 - e0);
        out[(size_t)n * DIM + lane] = (s - dg * heW) / fmaxf(dg, 1.0f);
    }
}

extern "C" void kernel_launch(void* const* d_in, const int* in_sizes, int n_in,
                              void* d_out, int out_size, void* d_ws, size_t ws_size,
                              hipStream_t stream) {
    const float* feat = (const float*)d_in[0];   // (N, 64)
    const float* h_e  = (const float*)d_in[1];   // (1, 64)
    const float* W    = (const float*)d_in[2];   // (64, 64)
    const int*   src  = (const int*)d_in[3];     // (E,)
    const int*   dst  = (const int*)d_in[4];     // (E,)

    const int n_edges = in_sizes[3];
    const int n_nodes = in_sizes[0] / DIM;

    float* out = (float*)d_out;

    const int nb   = (n_nodes + NPB - 1) >> NPB_LOG;
    const int epad = (n_edges + 3) & ~3;

    // ws: ccnt[1024] | ccur[1024] | coff[1028] | packed[epad] | featb[N*64 bf16]
    // (head = 3076 ints = 12304 B, 16-divisible; epad*4 16-divisible -> featb
    //  base is 16B-aligned for ushort4/uint4 access)
    const size_t need = ((size_t)(1024 + 1024 + 1028) + epad) * sizeof(int) +
                        (size_t)n_nodes * DIM * sizeof(ushort_t);
    const bool primary_ok = (n_nodes <= 65536) && (nb <= MAXNB) && (ws_size >= need);

    if (primary_ok) {
        int* ccnt   = (int*)d_ws;
        int* ccur   = ccnt + 1024;
        int* coff   = ccur + 1024;                 // 1028 slots
        int* packed = coff + 1028;
        ushort_t* featb = (ushort_t*)(packed + epad);

        cc_prep   <<<1024, 256, 0, stream>>>(feat, featb, n_nodes * DIM, ccnt);
        cc_count  <<<256,  256, 0, stream>>>(dst, ccnt, n_edges, nb);
        cc_scan   <<<1,    256, 0, stream>>>(ccnt, coff, ccur, nb);
        cc_scatter<<<256,  256, 0, stream>>>(src, dst, ccur, packed, n_edges, nb);
        cc_fused  <<<nb,   256, 0, stream>>>(featb, W, h_e, coff, packed, out, n_nodes);
    } else {
        // fallback: ws = deg_i[N] | cursor[N] | offsets[N+1] | edge_src[E]
        int* deg_i    = (int*)d_ws;
        int* cursor   = deg_i + n_nodes;
        int* offsets  = cursor + n_nodes;
        int* edge_src = offsets + (n_nodes + 1);

        hipMemsetAsync(deg_i, 0, (size_t)n_nodes * sizeof(int), stream);
        compconv_hist<<<1024, 256, 0, stream>>>(dst, deg_i, n_edges);
        compconv_scan1<<<1, 1024, 0, stream>>>(deg_i, offsets, cursor, n_nodes);
        compconv_bucket<<<1024, 256, 0, stream>>>(src, dst, cursor, edge_src, n_edges);
        compconv_gather<<<2048, 256, 0, stream>>>(feat, W, h_e, offsets, edge_src,
                                                  out, n_nodes);
    }
}